// Round 3
// baseline (422.659 us; speedup 1.0000x reference)
//
#include <hip/hip_runtime.h>
#include <hip/hip_bf16.h>

// Problem constants (fixed by the reference)
#define NN 50000
#define EE 800000
#define DIN 146
#define DD 128
#define GG 64
#define LL 4
#define NC 10
#define BN_EPS 1e-5f

#define KP_EMB 160    // 146 padded to multiple of 32
#define AST_L  136    // LDS A stride (shorts) for fused gemm
#define NCOPY 64      // stat accumulator copies (contention spreading)
#define NPW 4         // nodes per wave in agg

// ---- bucket CSR build (no global atomics) ----
#define NBKT 196      // ceil(NN/256) buckets of 256 nodes
#define BHP  200      // padded bucket-hist row stride (ints)
#define NBE  782      // edge blocks: ceil(EE/4/256)

// mega (A) block ranges: edge / init / repack / batch / params / wt
#define A_EDGE   NBE
#define A_INIT   (A_EDGE + 256)
#define A_REPACK (A_INIT + 3907)          // 50000*20 chunks of 8 cols
#define A_BATCH  (A_REPACK + 196)
#define A_PARAMS (A_BATCH + 384)
#define A_WT     (A_PARAMS + 400)

// C kernel: gemm blocks first, then scatter blocks
#define B_GEMM 391
#define C_TOT  (B_GEMM + NBE)

typedef __attribute__((ext_vector_type(8))) short bf16x8;
typedef __attribute__((ext_vector_type(4))) float f32x4;

__device__ __forceinline__ float bf2f(__hip_bfloat16 v) { return __bfloat162float(v); }
__device__ __forceinline__ float loadf(const void* p, long i, int f32) {
    return f32 ? ((const float*)p)[i] : bf2f(((const __hip_bfloat16*)p)[i]);
}
__device__ __forceinline__ unsigned short f2bf_bits(float f) {
    __hip_bfloat16 h = __float2bfloat16(f);
    return *(unsigned short*)&h;
}
__device__ __forceinline__ float bfu2f(unsigned short u) {
    return __uint_as_float((unsigned)u << 16);
}
__device__ __forceinline__ float lo16(unsigned v) { return __uint_as_float(v << 16); }
__device__ __forceinline__ float hi16(unsigned v) { return __uint_as_float(v & 0xffff0000u); }
__device__ __forceinline__ ushort4 pack4(f32x4 v) {
    ushort4 u;
    u.x = f2bf_bits(v[0]); u.y = f2bf_bits(v[1]);
    u.z = f2bf_bits(v[2]); u.w = f2bf_bits(v[3]);
    return u;
}
__device__ __forceinline__ ushort4 pack4s(f32x4 v, float s) {
    ushort4 u;
    u.x = f2bf_bits(s * v[0]); u.y = f2bf_bits(s * v[1]);
    u.z = f2bf_bits(s * v[2]); u.w = f2bf_bits(s * v[3]);
    return u;
}

// exclusive prefix over 256 threads; *total_sh gets block total (stable after call)
__device__ __forceinline__ int blk_excl_scan(int v, int t, int* wsum, int* total_sh) {
    __syncthreads();   // protect wsum/total reuse across consecutive calls
    int lane = t & 63, w = t >> 6;
    int x = v;
    #pragma unroll
    for (int s = 1; s < 64; s <<= 1) {
        int y = __shfl_up(x, s, 64);
        if (lane >= s) x += y;
    }
    if (lane == 63) wsum[w] = x;
    __syncthreads();
    if (t == 0) {
        int a = 0;
        #pragma unroll
        for (int k = 0; k < 4; ++k) { int tmp = wsum[k]; wsum[k] = a; a += tmp; }
        *total_sh = a;
    }
    __syncthreads();
    return x - v + wsum[w];
}

// flags[0]=edge_index int64, flags[1]=batch int64, flags[2]=floats are f32
__global__ void detect_kernel(const void* ei, const void* batch, const void* Wemb,
                              int* __restrict__ flags) {
    __shared__ int s_edge_nz, s_batch_nz, s_f32_cnt;
    int t = threadIdx.x;  // 64
    if (t == 0) { s_edge_nz = 0; s_batch_nz = 0; s_f32_cnt = 0; }
    __syncthreads();
    {   const int* w = (const int*)ei;
        long j = ((long)t * ((2L * EE) / 64)) | 1;
        if (w[j] != 0) atomicAdd(&s_edge_nz, 1);
    }
    {   const int* w = (const int*)batch;
        long j = ((long)(NN / 2) + (long)t * ((NN / 2) / 64)) | 1;
        if (j < NN && w[j] != 0) atomicAdd(&s_batch_nz, 1);
    }
    {   const unsigned short* w = (const unsigned short*)Wemb;
        unsigned short v = w[2 * t];
        int ex = (v >> 7) & 0xFF;
        if (v != 0 && ex >= 128) atomicAdd(&s_f32_cnt, 1);
    }
    __syncthreads();
    if (t == 0) {
        flags[0] = (s_edge_nz == 0) ? 1 : 0;
        flags[1] = (s_batch_nz == 0) ? 1 : 0;
        flags[2] = (s_f32_cnt >= 8) ? 1 : 0;
    }
}

struct Param { const void* src; float* dst; int src_n; int dst_n; };
struct Params12 { Param p[12]; };
struct WtDesc { const void* src; long src_off; unsigned short* dst; int K; int Kpad; };
struct WtDescs5 { WtDesc p[5]; };

// A: edge extract + bucket hist (LDS only) || conversions + zero-init
__global__ __launch_bounds__(256) void mega_conv_kernel(
    const void* __restrict__ x, const void* __restrict__ ei,
    const void* __restrict__ batch, const int* __restrict__ flags,
    unsigned short* __restrict__ xb, float* __restrict__ statmulti,
    float* __restrict__ hgsum, int* __restrict__ b32,
    unsigned* __restrict__ pk, unsigned char* __restrict__ bkt,
    int* __restrict__ bh, Params12 P, WtDescs5 W)
{
    int b = blockIdx.x;
    int t = threadIdx.x;
    if (b < A_EDGE) {
        __shared__ int hist[NBKT];
        if (t < NBKT) hist[t] = 0;
        __syncthreads();
        int e0 = (b * 256 + t) * 4;
        if (e0 < EE) {
            const int* w = (const int*)ei;
            int4 sv, dv;
            if (flags[0]) {
                int4 u0 = *(const int4*)(w + 2L * e0);
                int4 u1 = *(const int4*)(w + 2L * e0 + 4);
                int4 v0 = *(const int4*)(w + 2L * (EE + e0));
                int4 v1 = *(const int4*)(w + 2L * (EE + e0) + 4);
                sv = make_int4(u0.x, u0.z, u1.x, u1.z);
                dv = make_int4(v0.x, v0.z, v1.x, v1.z);
            } else {
                sv = *(const int4*)(w + e0);
                dv = *(const int4*)(w + EE + e0);
            }
            int ss[4] = {sv.x, sv.y, sv.z, sv.w};
            int dd2[4] = {dv.x, dv.y, dv.z, dv.w};
            unsigned pk4[4], bk4[4];
            #pragma unroll
            for (int k = 0; k < 4; ++k) {
                unsigned s = min((unsigned)ss[k], (unsigned)(NN - 1));
                unsigned d = min((unsigned)dd2[k], (unsigned)(NN - 1));
                pk4[k] = (s << 8) | (d & 255u);
                bk4[k] = d >> 8;
                atomicAdd(&hist[bk4[k]], 1);
            }
            *(uint4*)(pk + e0) = make_uint4(pk4[0], pk4[1], pk4[2], pk4[3]);
            *(uchar4*)(bkt + e0) = make_uchar4((unsigned char)bk4[0], (unsigned char)bk4[1],
                                               (unsigned char)bk4[2], (unsigned char)bk4[3]);
        }
        __syncthreads();
        if (t < NBKT) bh[b * BHP + t] = hist[t];
    } else if (b < A_INIT) {
        int i = (b - A_EDGE) * 256 + t;
        if (i < LL * NCOPY * 256) statmulti[i] = 0.0f;
        if (i < GG * DD) hgsum[i] = 0.0f;
    } else if (b < A_REPACK) {
        // 8 cols per thread: float2/uint reads, one uint4 (16B) store
        int f32 = flags[2];
        long idx8 = (long)(b - A_INIT) * 256 + t;
        if (idx8 < (long)NN * 20) {
            int row = (int)(idx8 / 20);
            int c8 = (int)(idx8 - (long)row * 20) * 8;
            float v[8];
            if (c8 + 8 <= DIN) {
                if (f32) {
                    const float* xp = (const float*)x + (long)row * DIN + c8;
                    #pragma unroll
                    for (int k2 = 0; k2 < 4; ++k2) {
                        float2 f = *(const float2*)(xp + 2 * k2);  // 8B-aligned: 146*4%8==0
                        v[2 * k2] = f.x; v[2 * k2 + 1] = f.y;
                    }
                } else {
                    const unsigned* xp = (const unsigned*)((const unsigned short*)x +
                                                           (long)row * DIN + c8);
                    #pragma unroll
                    for (int k2 = 0; k2 < 4; ++k2) {
                        unsigned u = xp[k2];  // 4B-aligned: 146*2%4==0
                        v[2 * k2] = bfu2f((unsigned short)u);
                        v[2 * k2 + 1] = bfu2f((unsigned short)(u >> 16));
                    }
                }
            } else {
                #pragma unroll
                for (int k = 0; k < 8; ++k) {
                    int col = c8 + k;
                    v[k] = (col < DIN) ? loadf(x, (long)row * DIN + col, f32) : 0.0f;
                }
            }
            unsigned o[4];
            #pragma unroll
            for (int k2 = 0; k2 < 4; ++k2)
                o[k2] = (unsigned)f2bf_bits(v[2 * k2]) |
                        ((unsigned)f2bf_bits(v[2 * k2 + 1]) << 16);
            *(uint4*)(xb + (long)row * KP_EMB + c8) = make_uint4(o[0], o[1], o[2], o[3]);
        }
    } else if (b < A_BATCH) {
        int i = (b - A_REPACK) * 256 + t;
        if (i < NN) b32[i] = flags[1] ? ((const int*)batch)[2L * i] : ((const int*)batch)[i];
    } else if (b < A_PARAMS) {
        int f32 = flags[2];
        int bb = b - A_BATCH;
        const Param& e = P.p[bb >> 5];
        int idx = (bb & 31) * 256 + t;
        if (idx < e.dst_n)
            e.dst[idx] = (idx < e.src_n) ? loadf(e.src, idx, f32) : 0.0f;
    } else {
        int f32 = flags[2];
        int bb = b - A_PARAMS;
        int y = bb / 80;
        const WtDesc& e = W.p[y];
        int idx = (bb - y * 80) * 256 + t;
        if (idx < 128 * e.Kpad) {
            int n = idx / e.Kpad, k = idx - n * e.Kpad;
            float v = (k < e.K) ? loadf(e.src, e.src_off + (long)k * DD + n, f32) : 0.0f;
            e.dst[idx] = f2bf_bits(v);
        }
    }
}

// B1: per bucket, exclusive-scan bh[0..NBE) column; write back in place; tot[b]=sum
__global__ __launch_bounds__(256) void bscan_kernel(int* __restrict__ bh, int* __restrict__ tot) {
    __shared__ int wsum[4], total_sh;
    int b = blockIdx.x;
    int t = threadIdx.x;
    int carry = 0;
    #pragma unroll 1
    for (int c = 0; c < 4; ++c) {
        int i = c * 256 + t;
        int v = (i < NBE) ? bh[i * BHP + b] : 0;
        int excl = blk_excl_scan(v, t, wsum, &total_sh);
        if (i < NBE) bh[i * BHP + b] = excl + carry;
        carry += total_sh;
    }
    if (t == 0) tot[b] = carry;
}

// B2: scan bucket totals -> base[0..NBKT]; base[NBKT]=E; off[NN]=E
__global__ void bscan2_kernel(const int* __restrict__ tot, int* __restrict__ base,
                              int* __restrict__ off_last) {
    __shared__ int wsum[4], total_sh;
    int t = threadIdx.x;  // 256
    int v = (t < NBKT) ? tot[t] : 0;
    int excl = blk_excl_scan(v, t, wsum, &total_sh);
    if (t < NBKT) base[t] = excl;
    if (t == 0) { base[NBKT] = total_sh; *off_last = total_sh; }
}

// ---- MFMA layouts (operand-SWAPPED form) ----
// mfma(b_frag, a_frag, acc): acc reg rg of slot t8 holds output col t8*16+quad*4+rg
// for node row rbase+rt*16+m  -> 4 consecutive cols per fragment = ushort4 store.

// C: emb MFMA gemm (blocks 0..390) || bucket scatter via LDS cursors (391..1172)
__global__ __launch_bounds__(256) void bucket_emb_kernel(
    const unsigned* __restrict__ pk, const unsigned char* __restrict__ bkt,
    const int* __restrict__ bh, const int* __restrict__ base,
    unsigned* __restrict__ bucketA,
    const unsigned short* __restrict__ Ab,   // xb [n][160] bf16
    const unsigned short* __restrict__ Wt,   // [128][160] bf16 transposed
    const float* __restrict__ bias,
    unsigned short* __restrict__ hb, int n)
{
    int t = threadIdx.x;
    if (blockIdx.x >= B_GEMM) {
        int bb = blockIdx.x - B_GEMM;
        __shared__ int cur[NBKT];
        if (t < NBKT) cur[t] = bh[bb * BHP + t] + base[t];
        __syncthreads();
        int e0 = (bb * 256 + t) * 4;
        if (e0 < EE) {
            uint4 p4 = *(const uint4*)(pk + e0);
            uchar4 b4 = *(const uchar4*)(bkt + e0);
            unsigned pks[4] = {p4.x, p4.y, p4.z, p4.w};
            unsigned bks[4] = {b4.x, b4.y, b4.z, b4.w};
            #pragma unroll
            for (int k = 0; k < 4; ++k) {
                int slot = atomicAdd(&cur[bks[k]], 1);
                bucketA[slot] = pks[k];
            }
        }
        return;
    }
    int r0 = blockIdx.x * 128;
    int lane = t & 63, w = t >> 6;
    int m = lane & 15, quad = lane >> 4;
    int rbase = r0 + w * 32;
    bf16x8 a[2][5];
    #pragma unroll
    for (int rt = 0; rt < 2; ++rt)
        #pragma unroll
        for (int c = 0; c < 5; ++c) {
            int rr = rbase + rt * 16 + m; if (rr > n - 1) rr = n - 1;
            a[rt][c] = *(const bf16x8*)(Ab + (long)rr * KP_EMB + c * 32 + quad * 8);
        }
    f32x4 acc[2][8];
    #pragma unroll
    for (int t8 = 0; t8 < 8; ++t8) {
        float4 bv = *(const float4*)&bias[t8 * 16 + quad * 4];
        f32x4 ai = {bv.x, bv.y, bv.z, bv.w};
        acc[0][t8] = ai; acc[1][t8] = ai;
    }
    #pragma unroll
    for (int t8 = 0; t8 < 8; ++t8) {
        #pragma unroll
        for (int c = 0; c < 5; ++c) {
            bf16x8 b = *(const bf16x8*)(Wt + (long)(t8 * 16 + m) * KP_EMB + c * 32 + quad * 8);
            acc[0][t8] = __builtin_amdgcn_mfma_f32_16x16x32_bf16(b, a[0][c], acc[0][t8], 0, 0, 0);
            acc[1][t8] = __builtin_amdgcn_mfma_f32_16x16x32_bf16(b, a[1][c], acc[1][t8], 0, 0, 0);
        }
    }
    #pragma unroll
    for (int rt = 0; rt < 2; ++rt) {
        int row = rbase + rt * 16 + m;
        if (row < n) {
            #pragma unroll
            for (int t8 = 0; t8 < 8; ++t8)
                *(ushort4*)(hb + (long)row * DD + t8 * 16 + quad * 4) = pack4(acc[rt][t8]);
        }
    }
}

// D: per-bucket CSR: LDS degree hist -> off/dinv; LDS cursors -> src_s
__global__ __launch_bounds__(256) void csr_kernel(
    const unsigned* __restrict__ bucketA, const int* __restrict__ base,
    int* __restrict__ off, float* __restrict__ dinv, int* __restrict__ src_s)
{
    __shared__ int dg[256], cur[256], wsum[4], total_sh;
    int b = blockIdx.x, t = threadIdx.x;
    int eb0 = base[b], eb1 = base[b + 1];
    dg[t] = 0;
    __syncthreads();
    for (int e = eb0 + t; e < eb1; e += 256)
        atomicAdd(&dg[bucketA[e] & 255u], 1);
    __syncthreads();
    int v = dg[t];
    int excl = blk_excl_scan(v, t, wsum, &total_sh);
    int node = b * 256 + t;
    if (node < NN) {
        off[node] = eb0 + excl;
        dinv[node] = rsqrtf((float)(v + 1));  // +1 self-loop
    }
    cur[t] = excl;
    __syncthreads();
    for (int e = eb0 + t; e < eb1; e += 256) {
        unsigned pv = bucketA[e];
        int r = atomicAdd(&cur[pv & 255u], 1);
        src_s[eb0 + r] = (int)(pv >> 8);
    }
}

// E: layer-0 gemm (mb = dinv * hb . W0)
__global__ __launch_bounds__(256) void gemm_plain_kernel(
    const unsigned short* __restrict__ Ab,   // hb
    const unsigned short* __restrict__ Wt,   // wt_gcn layer 0
    const float* __restrict__ dinv,
    unsigned short* __restrict__ Mb, int n)
{
    int t = threadIdx.x;
    int r0 = blockIdx.x * 128;
    int lane = t & 63, w = t >> 6;
    int m = lane & 15, quad = lane >> 4;
    int rbase = r0 + w * 32;
    bf16x8 a[2][4];
    #pragma unroll
    for (int rt = 0; rt < 2; ++rt)
        #pragma unroll
        for (int c = 0; c < 4; ++c) {
            int rr = rbase + rt * 16 + m; if (rr > n - 1) rr = n - 1;
            a[rt][c] = *(const bf16x8*)(Ab + (long)rr * DD + c * 32 + quad * 8);
        }
    float dvt[2];
    int rowt[2];
    #pragma unroll
    for (int rt = 0; rt < 2; ++rt) {
        int rr = rbase + rt * 16 + m;
        rowt[rt] = rr;
        if (rr > n - 1) rr = n - 1;
        dvt[rt] = dinv[rr];
    }
    f32x4 acc[2][8];
    #pragma unroll
    for (int t8 = 0; t8 < 8; ++t8) {
        f32x4 z = {0.f, 0.f, 0.f, 0.f};
        acc[0][t8] = z; acc[1][t8] = z;
    }
    #pragma unroll
    for (int t8 = 0; t8 < 8; ++t8) {
        #pragma unroll
        for (int c = 0; c < 4; ++c) {
            bf16x8 b = *(const bf16x8*)(Wt + (long)(t8 * 16 + m) * DD + c * 32 + quad * 8);
            acc[0][t8] = __builtin_amdgcn_mfma_f32_16x16x32_bf16(b, a[0][c], acc[0][t8], 0, 0, 0);
            acc[1][t8] = __builtin_amdgcn_mfma_f32_16x16x32_bf16(b, a[1][c], acc[1][t8], 0, 0, 0);
        }
    }
    #pragma unroll
    for (int rt = 0; rt < 2; ++rt) {
        if (rowt[rt] < n) {
            #pragma unroll
            for (int t8 = 0; t8 < 8; ++t8)
                *(ushort4*)(Mb + (long)rowt[rt] * DD + t8 * 16 + quad * 4) = pack4s(acc[rt][t8], dvt[rt]);
        }
    }
}

// fused: inline stats-finalize + hb += relu(bn(aggb)) (bf16 in-place) + MFMA
__global__ __launch_bounds__(256) void gemm_fused_kernel(
    const unsigned short* __restrict__ aggb, unsigned short* __restrict__ hb,
    const float* __restrict__ statmulti, const float* __restrict__ gamma,
    const float* __restrict__ beta, const float* __restrict__ dinv,
    const unsigned short* __restrict__ Wt, unsigned short* __restrict__ Mb, int n)
{
    __shared__ unsigned short As[128 * AST_L];
    __shared__ float bnsh[256];
    int t = threadIdx.x;
    int r0 = blockIdx.x * 128;
    {
        float s = 0.0f;
        #pragma unroll 8
        for (int k = 0; k < NCOPY; ++k) s += statmulti[k * 256 + t];
        bnsh[t] = s;
    }
    __syncthreads();
    {
        int c4 = (t & 31) * 4, rsub = t >> 5;  // 8 row substreams
        float inv_n = 1.0f / (float)n;
        float4 sm = *(const float4*)&bnsh[c4];
        float4 sq = *(const float4*)&bnsh[128 + c4];
        float4 ga = *(const float4*)&gamma[c4];
        float4 be = *(const float4*)&beta[c4];
        float4 mu, rs;
        mu.x = sm.x * inv_n; mu.y = sm.y * inv_n; mu.z = sm.z * inv_n; mu.w = sm.w * inv_n;
        rs.x = rsqrtf(sq.x * inv_n - mu.x * mu.x + BN_EPS) * ga.x;
        rs.y = rsqrtf(sq.y * inv_n - mu.y * mu.y + BN_EPS) * ga.y;
        rs.z = rsqrtf(sq.z * inv_n - mu.z * mu.z + BN_EPS) * ga.z;
        rs.w = rsqrtf(sq.w * inv_n - mu.w * mu.w + BN_EPS) * ga.w;
        #pragma unroll 4
        for (int i = 0; i < 16; ++i) {
            int row = i * 8 + rsub;
            int r = r0 + row;
            unsigned short o0 = 0, o1 = 0, o2 = 0, o3 = 0;
            if (r < n) {
                long g = (long)r * DD + c4;
                ushort4 au = *(const ushort4*)&aggb[g];
                ushort4 hu = *(const ushort4*)&hb[g];
                float h0 = bfu2f(hu.x) + fmaxf((bfu2f(au.x) - mu.x) * rs.x + be.x, 0.0f);
                float h1 = bfu2f(hu.y) + fmaxf((bfu2f(au.y) - mu.y) * rs.y + be.y, 0.0f);
                float h2 = bfu2f(hu.z) + fmaxf((bfu2f(au.z) - mu.z) * rs.z + be.z, 0.0f);
                float h3 = bfu2f(hu.w) + fmaxf((bfu2f(au.w) - mu.w) * rs.w + be.w, 0.0f);
                o0 = f2bf_bits(h0); o1 = f2bf_bits(h1);
                o2 = f2bf_bits(h2); o3 = f2bf_bits(h3);
                ushort4 ho; ho.x = o0; ho.y = o1; ho.z = o2; ho.w = o3;
                *(ushort4*)&hb[g] = ho;
            }
            unsigned short* dst = &As[row * AST_L + c4];
            dst[0] = o0; dst[1] = o1; dst[2] = o2; dst[3] = o3;
        }
    }
    __syncthreads();
    int lane = t & 63, w = t >> 6;
    int m = lane & 15, quad = lane >> 4;
    int rl = w * 32;
    int rbase = r0 + rl;
    bf16x8 a[2][4];
    #pragma unroll
    for (int rt = 0; rt < 2; ++rt)
        #pragma unroll
        for (int c = 0; c < 4; ++c)
            a[rt][c] = *(const bf16x8*)(As + (rl + rt * 16 + m) * AST_L + c * 32 + quad * 8);
    float dvt[2];
    int rowt[2];
    #pragma unroll
    for (int rt = 0; rt < 2; ++rt) {
        int rr = rbase + rt * 16 + m;
        rowt[rt] = rr;
        if (rr > n - 1) rr = n - 1;
        dvt[rt] = dinv[rr];
    }
    f32x4 acc[2][8];
    #pragma unroll
    for (int t8 = 0; t8 < 8; ++t8) {
        f32x4 z = {0.f, 0.f, 0.f, 0.f};
        acc[0][t8] = z; acc[1][t8] = z;
    }
    #pragma unroll
    for (int t8 = 0; t8 < 8; ++t8) {
        #pragma unroll
        for (int c = 0; c < 4; ++c) {
            bf16x8 b = *(const bf16x8*)(Wt + (long)(t8 * 16 + m) * DD + c * 32 + quad * 8);
            acc[0][t8] = __builtin_amdgcn_mfma_f32_16x16x32_bf16(b, a[0][c], acc[0][t8], 0, 0, 0);
            acc[1][t8] = __builtin_amdgcn_mfma_f32_16x16x32_bf16(b, a[1][c], acc[1][t8], 0, 0, 0);
        }
    }
    #pragma unroll
    for (int rt = 0; rt < 2; ++rt) {
        if (rowt[rt] < n) {
            #pragma unroll
            for (int t8 = 0; t8 < 8; ++t8)
                *(ushort4*)(Mb + (long)rowt[rt] * DD + t8 * 16 + quad * 4) = pack4s(acc[rt][t8], dvt[rt]);
        }
    }
}

// agg: wave-per-node, lane owns cols (2l,2l+1). Per edge: 64 lanes x 4B = one
// coalesced 256B row read. No LDS reduce. 8 gathers in flight per unrolled step.
__global__ __launch_bounds__(256) void agg_kernel(
    const unsigned* __restrict__ mb32, const int* __restrict__ off,
    const int* __restrict__ src_s,
    const float* __restrict__ dinv, const float* __restrict__ bias,
    unsigned* __restrict__ aggb32, float* __restrict__ statacc)
{
    __shared__ float2 ssum[4][64], ssq[4][64];
    int t = threadIdx.x;
    int wv = t >> 6, lane = t & 63;
    float2 bi = ((const float2*)bias)[lane];
    float2 sAcc = {0.0f, 0.0f}, qAcc = {0.0f, 0.0f};
    int i0 = (blockIdx.x * 4 + wv) * NPW;
    #pragma unroll 1
    for (int ni = 0; ni < NPW; ++ni) {
        int i = i0 + ni;
        if (i >= NN) break;
        int e = off[i], e1 = off[i + 1];
        unsigned vs = mb32[(long)i * 64 + lane];   // self-loop term
        float a0 = lo16(vs), a1 = hi16(vs);
        for (; e + 8 <= e1; e += 8) {
            int j0 = src_s[e + 0], j1 = src_s[e + 1], j2 = src_s[e + 2], j3 = src_s[e + 3];
            int j4 = src_s[e + 4], j5 = src_s[e + 5], j6 = src_s[e + 6], j7 = src_s[e + 7];
            unsigned v0 = mb32[(long)j0 * 64 + lane];
            unsigned v1 = mb32[(long)j1 * 64 + lane];
            unsigned v2 = mb32[(long)j2 * 64 + lane];
            unsigned v3 = mb32[(long)j3 * 64 + lane];
            unsigned v4 = mb32[(long)j4 * 64 + lane];
            unsigned v5 = mb32[(long)j5 * 64 + lane];
            unsigned v6 = mb32[(long)j6 * 64 + lane];
            unsigned v7 = mb32[(long)j7 * 64 + lane];
            a0 += lo16(v0); a1 += hi16(v0);
            a0 += lo16(v1); a1 += hi16(v1);
            a0 += lo16(v2); a1 += hi16(v2);
            a0 += lo16(v3); a1 += hi16(v3);
            a0 += lo16(v4); a1 += hi16(v4);
            a0 += lo16(v5); a1 += hi16(v5);
            a0 += lo16(v6); a1 += hi16(v6);
            a0 += lo16(v7); a1 += hi16(v7);
        }
        for (; e + 4 <= e1; e += 4) {
            int j0 = src_s[e + 0], j1 = src_s[e + 1], j2 = src_s[e + 2], j3 = src_s[e + 3];
            unsigned v0 = mb32[(long)j0 * 64 + lane];
            unsigned v1 = mb32[(long)j1 * 64 + lane];
            unsigned v2 = mb32[(long)j2 * 64 + lane];
            unsigned v3 = mb32[(long)j3 * 64 + lane];
            a0 += lo16(v0); a1 += hi16(v0);
            a0 += lo16(v1); a1 += hi16(v1);
            a0 += lo16(v2); a1 += hi16(v2);
            a0 += lo16(v3); a1 += hi16(v3);
        }
        for (; e < e1; ++e) {
            int j = src_s[e];
            unsigned v = mb32[(long)j * 64 + lane];
            a0 += lo16(v); a1 += hi16(v);
        }
        float di = dinv[i];
        float o0 = fmaf(di, a0, bi.x);
        float o1 = fmaf(di, a1, bi.y);
        aggb32[(long)i * 64 + lane] = ((unsigned)f2bf_bits(o1) << 16) | f2bf_bits(o0);
        sAcc.x += o0; sAcc.y += o1;
        qAcc.x += o0 * o0; qAcc.y += o1 * o1;
    }
    ssum[wv][lane] = sAcc; ssq[wv][lane] = qAcc;
    __syncthreads();
    if (wv == 0) {
        float2 s0 = ssum[0][lane], s1 = ssum[1][lane], s2 = ssum[2][lane], s3 = ssum[3][lane];
        float2 q0 = ssq[0][lane], q1 = ssq[1][lane], q2 = ssq[2][lane], q3 = ssq[3][lane];
        float sx = s0.x + s1.x + s2.x + s3.x;
        float sy = s0.y + s1.y + s2.y + s3.y;
        float qx = q0.x + q1.x + q2.x + q3.x;
        float qy = q0.y + q1.y + q2.y + q3.y;
        float* copy = statacc + (blockIdx.x & (NCOPY - 1)) * 256;
        atomicAdd(&copy[2 * lane], sx);
        atomicAdd(&copy[2 * lane + 1], sy);
        atomicAdd(&copy[128 + 2 * lane], qx);
        atomicAdd(&copy[128 + 2 * lane + 1], qy);
    }
}

// pooling with inline stats-finalize + fused final BN+relu+residual (bf16 inputs)
__global__ void pool1_kernel(const unsigned short* __restrict__ hb,
                             const unsigned short* __restrict__ aggb,
                             const float* __restrict__ statmulti,
                             const float* __restrict__ gamma, const float* __restrict__ beta,
                             const int* __restrict__ b32, float* __restrict__ hgsum, int n) {
    __shared__ float bnsh[256];
    int t = threadIdx.x;
    {
        float s = 0.0f;
        #pragma unroll 8
        for (int k = 0; k < NCOPY; ++k) s += statmulti[k * 256 + t];
        bnsh[t] = s;
    }
    __syncthreads();
    int c4 = (t & 31) * 4, rsub = t >> 5;
    float inv_n = 1.0f / (float)n;
    float4 sm = *(const float4*)&bnsh[c4];
    float4 sq = *(const float4*)&bnsh[128 + c4];
    float4 ga = *(const float4*)&gamma[c4];
    float4 be = *(const float4*)&beta[c4];
    float4 mu, rs;
    mu.x = sm.x * inv_n; mu.y = sm.y * inv_n; mu.z = sm.z * inv_n; mu.w = sm.w * inv_n;
    rs.x = rsqrtf(sq.x * inv_n - mu.x * mu.x + BN_EPS) * ga.x;
    rs.y = rsqrtf(sq.y * inv_n - mu.y * mu.y + BN_EPS) * ga.y;
    rs.z = rsqrtf(sq.z * inv_n - mu.z * mu.z + BN_EPS) * ga.z;
    rs.w = rsqrtf(sq.w * inv_n - mu.w * mu.w + BN_EPS) * ga.w;
    int rows_pb = (n + gridDim.x - 1) / gridDim.x;
    int r0 = blockIdx.x * rows_pb;
    int r1 = min(n, r0 + rows_pb);
    float4 acc = {0, 0, 0, 0};
    int gcur = -1;
    for (int r = r0 + rsub; r < r1; r += 8) {
        int g = b32[r];
        if (g != gcur) {
            if (gcur >= 0) {
                atomicAdd(&hgsum[gcur * DD + c4 + 0], acc.x);
                atomicAdd(&hgsum[gcur * DD + c4 + 1], acc.y);
                atomicAdd(&hgsum[gcur * DD + c4 + 2], acc.z);
                atomicAdd(&hgsum[gcur * DD + c4 + 3], acc.w);
            }
            acc.x = acc.y = acc.z = acc.w = 0.0f;
            gcur = ((unsigned)g < (unsigned)GG) ? g : -1;
        }
        if (gcur >= 0) {
            long ix = (long)r * DD + c4;
            ushort4 au = *(const ushort4*)&aggb[ix];
            ushort4 hu = *(const ushort4*)&hb[ix];
            acc.x += bfu2f(hu.x) + fmaxf((bfu2f(au.x) - mu.x) * rs.x + be.x, 0.0f);
            acc.y += bfu2f(hu.y) + fmaxf((bfu2f(au.y) - mu.y) * rs.y + be.y, 0.0f);
            acc.z += bfu2f(hu.z) + fmaxf((bfu2f(au.z) - mu.z) * rs.z + be.z, 0.0f);
            acc.w += bfu2f(hu.w) + fmaxf((bfu2f(au.w) - mu.w) * rs.w + be.w, 0.0f);
        }
    }
    if (gcur >= 0) {
        atomicAdd(&hgsum[gcur * DD + c4 + 0], acc.x);
        atomicAdd(&hgsum[gcur * DD + c4 + 1], acc.y);
        atomicAdd(&hgsum[gcur * DD + c4 + 2], acc.z);
        atomicAdd(&hgsum[gcur * DD + c4 + 3], acc.w);
    }
}

__device__ int lower_bound_i(const int* __restrict__ a, int n, int v) {
    int lo = 0, hi = n;
    while (lo < hi) {
        int mid = (lo + hi) >> 1;
        if (a[mid] < v) lo = mid + 1; else hi = mid;
    }
    return lo;
}

// readout with fused mean-pool finalize
__global__ void readout_kernel(const float* __restrict__ hgsum, const int* __restrict__ b32,
                               const float* __restrict__ W1, const float* __restrict__ b1,
                               const float* __restrict__ W2, const float* __restrict__ b2,
                               const float* __restrict__ W3, const float* __restrict__ b3,
                               const int* __restrict__ flags, void* __restrict__ out, int n) {
    int f32 = flags[2];
    int g = blockIdx.x;
    int t = threadIdx.x;
    __shared__ float hgs[DD];
    __shared__ float z1[DD / 2];
    __shared__ float z2[DD / 4];
    int lo = lower_bound_i(b32, n, g);
    int hi = lower_bound_i(b32, n, g + 1);
    float invc = 1.0f / fmaxf((float)(hi - lo), 1.0f);
    hgs[t] = hgsum[g * DD + t] * invc;
    __syncthreads();
    if (t < DD / 2) {
        float acc = b1[t];
        #pragma unroll 8
        for (int k = 0; k < DD; ++k) acc = fmaf(hgs[k], W1[k * (DD / 2) + t], acc);
        z1[t] = fmaxf(acc, 0.0f);
    }
    __syncthreads();
    if (t < DD / 4) {
        float acc = b2[t];
        #pragma unroll 8
        for (int k = 0; k < DD / 2; ++k) acc = fmaf(z1[k], W2[k * (DD / 4) + t], acc);
        z2[t] = fmaxf(acc, 0.0f);
    }
    __syncthreads();
    if (t < NC) {
        float acc = b3[t];
        #pragma unroll 8
        for (int k = 0; k < DD / 4; ++k) acc = fmaf(z2[k], W3[k * NC + t], acc);
        if (f32) ((float*)out)[g * NC + t] = acc;
        else     ((__hip_bfloat16*)out)[g * NC + t] = __float2bfloat16(acc);
    }
}

extern "C" void kernel_launch(void* const* d_in, const int* in_sizes, int n_in,
                              void* d_out, int out_size, void* d_ws, size_t ws_size,
                              hipStream_t stream) {
    const void* x      = d_in[0];
    const void* ei     = d_in[1];
    const void* batch  = d_in[2];
    const void* W_emb  = d_in[3];
    const void* b_emb  = d_in[4];
    const void* W_gcn  = d_in[5];
    const void* b_gcn  = d_in[6];
    const void* bn_g   = d_in[7];
    const void* bn_b   = d_in[8];
    const void* W_r1   = d_in[9];
    const void* b_r1   = d_in[10];
    const void* W_r2   = d_in[11];
    const void* b_r2   = d_in[12];
    const void* W_r3   = d_in[13];
    const void* b_r3   = d_in[14];

    char* p = (char*)d_ws;
    auto alloc = [&](size_t bytes) -> void* {
        void* r = (void*)p;
        p += (bytes + 255) & ~(size_t)255;
        return r;
    };
    int*   flags  = (int*)alloc(64 * 4);
    float* statmulti = (float*)alloc((size_t)LL * NCOPY * 256 * 4);
    float* hgsum  = (float*)alloc((size_t)GG * DD * 4);
    int*   off    = (int*)alloc((size_t)(NN + 1) * 4);
    float* dinv   = (float*)alloc((size_t)NN * 4);
    int*   b32    = (int*)alloc((size_t)NN * 4);
    int*   src_s  = (int*)alloc((size_t)EE * 4);
    unsigned* pk  = (unsigned*)alloc((size_t)EE * 4);
    unsigned char* bkt = (unsigned char*)alloc((size_t)EE);
    int*   bh     = (int*)alloc((size_t)NBE * BHP * 4);
    int*   tot    = (int*)alloc(256 * 4);
    int*   base   = (int*)alloc(256 * 4);
    unsigned* bucketA = (unsigned*)alloc((size_t)EE * 4);
    unsigned short* hb = (unsigned short*)alloc((size_t)NN * DD * 2);
    unsigned short* mb = (unsigned short*)alloc((size_t)NN * DD * 2);
    unsigned short* aggb = (unsigned short*)alloc((size_t)NN * DD * 2);
    unsigned short* xb = (unsigned short*)alloc((size_t)NN * KP_EMB * 2);
    // canonical params
    unsigned short* wt_emb = (unsigned short*)alloc((size_t)DD * KP_EMB * 2);
    unsigned short* wt_gcn = (unsigned short*)alloc((size_t)LL * DD * DD * 2);
    float* b_emb32 = (float*)alloc(DD * 4);
    float* b_gcn32 = (float*)alloc((size_t)LL * DD * 4);
    float* bng32   = (float*)alloc((size_t)LL * DD * 4);
    float* bnb32   = (float*)alloc((size_t)LL * DD * 4);
    float* wr1     = (float*)alloc((size_t)DD * (DD / 2) * 4);
    float* br1     = (float*)alloc((DD / 2) * 4);
    float* wr2     = (float*)alloc((size_t)(DD / 2) * (DD / 4) * 4);
    float* br2     = (float*)alloc((DD / 4) * 4);
    float* wr3     = (float*)alloc((size_t)(DD / 4) * NC * 4);
    float* br3     = (float*)alloc(NC * 4);

    detect_kernel<<<1, 64, 0, stream>>>(ei, batch, W_emb, flags);

    Params12 P;
    P.p[0]  = { b_emb, b_emb32, DD, DD };
    P.p[1]  = { b_gcn, b_gcn32, LL * DD, LL * DD };
    P.p[2]  = { bn_g,  bng32,   LL * DD, LL * DD };
    P.p[3]  = { bn_b,  bnb32,   LL * DD, LL * DD };
    P.p[4]  = { W_r1,  wr1,     DD * (DD / 2), DD * (DD / 2) };
    P.p[5]  = { b_r1,  br1,     DD / 2, DD / 2 };
    P.p[6]  = { W_r2,  wr2,     (DD / 2) * (DD / 4), (DD / 2) * (DD / 4) };
    P.p[7]  = { b_r2,  br2,     DD / 4, DD / 4 };
    P.p[8]  = { W_r3,  wr3,     (DD / 4) * NC, (DD / 4) * NC };
    P.p[9]  = { b_r3,  br3,     NC, NC };
    P.p[10] = { b_r3,  br3,     0, 0 };
    P.p[11] = { b_r3,  br3,     0, 0 };

    WtDescs5 W;
    W.p[0] = { W_emb, 0,            wt_emb,                DIN, KP_EMB };
    W.p[1] = { W_gcn, 0L * DD * DD, wt_gcn + 0L * DD * DD, DD,  DD };
    W.p[2] = { W_gcn, 1L * DD * DD, wt_gcn + 1L * DD * DD, DD,  DD };
    W.p[3] = { W_gcn, 2L * DD * DD, wt_gcn + 2L * DD * DD, DD,  DD };
    W.p[4] = { W_gcn, 3L * DD * DD, wt_gcn + 3L * DD * DD, DD,  DD };

    mega_conv_kernel<<<A_WT, 256, 0, stream>>>(x, ei, batch, flags, xb, statmulti,
                                               hgsum, b32, pk, bkt, bh, P, W);

    bscan_kernel<<<NBKT, 256, 0, stream>>>(bh, tot);
    bscan2_kernel<<<1, 256, 0, stream>>>(tot, base, off + NN);

    bucket_emb_kernel<<<C_TOT, 256, 0, stream>>>(pk, bkt, bh, base, bucketA,
                                                 xb, wt_emb, b_emb32, hb, NN);

    csr_kernel<<<NBKT, 256, 0, stream>>>(bucketA, base, off, dinv, src_s);

    gemm_plain_kernel<<<(NN + 127) / 128, 256, 0, stream>>>(hb, wt_gcn, dinv, mb, NN);

    int ngemm = (NN + 127) / 128;  // 391
    int nagg = (NN + 4 * NPW - 1) / (4 * NPW);  // 3125 blocks (16 nodes/block)
    for (int l = 0; l < LL; ++l) {
        if (l > 0) {
            gemm_fused_kernel<<<ngemm, 256, 0, stream>>>(
                aggb, hb, statmulti + (size_t)(l - 1) * NCOPY * 256,
                bng32 + (l - 1) * DD, bnb32 + (l - 1) * DD,
                dinv, wt_gcn + (size_t)l * DD * DD, mb, NN);
        }
        agg_kernel<<<nagg, 256, 0, stream>>>((const unsigned*)mb, off, src_s, dinv,
                                             b_gcn32 + l * DD, (unsigned*)aggb,
                                             statmulti + (size_t)l * NCOPY * 256);
    }

    pool1_kernel<<<512, 256, 0, stream>>>(hb, aggb, statmulti + (size_t)(LL - 1) * NCOPY * 256,
                                          bng32 + (LL - 1) * DD, bnb32 + (LL - 1) * DD,
                                          b32, hgsum, NN);
    readout_kernel<<<GG, DD, 0, stream>>>(hgsum, b32, wr1, br1, wr2, br2, wr3, br3,
                                          flags, d_out, NN);
}

// Round 4
// 402.048 us; speedup vs baseline: 1.0513x; 1.0513x over previous
//
#include <hip/hip_runtime.h>
#include <hip/hip_bf16.h>

// Problem constants (fixed by the reference)
#define NN 50000
#define EE 800000
#define DIN 146
#define DD 128
#define GG 64
#define LL 4
#define NC 10
#define BN_EPS 1e-5f

#define KP_EMB 160    // 146 padded to multiple of 32
#define AST_L  136    // LDS A stride (shorts) for fused gemm
#define NCOPY 64      // stat accumulator copies (contention spreading)
#define NPW 4         // nodes per wave in agg

// ---- bucket CSR build (no global atomics) ----
#define NBKT 196      // ceil(NN/256) buckets of 256 nodes
#define BHP  200      // padded bucket-hist row stride (ints)
#define NBE  782      // edge blocks: ceil(EE/4/256)

// mega (A) block ranges: edge / init / repack / batch / params / wt
#define A_EDGE   NBE
#define A_INIT   (A_EDGE + 256)
#define A_REPACK (A_INIT + 3907)          // 50000*20 chunks of 8 cols
#define A_BATCH  (A_REPACK + 196)
#define A_PARAMS (A_BATCH + 384)
#define A_WT     (A_PARAMS + 400)

// C kernel: gemm blocks first, then scatter blocks
#define B_GEMM 391
#define C_TOT  (B_GEMM + NBE)

typedef __attribute__((ext_vector_type(8))) short bf16x8;
typedef __attribute__((ext_vector_type(4))) float f32x4;

__device__ __forceinline__ float bf2f(__hip_bfloat16 v) { return __bfloat162float(v); }
__device__ __forceinline__ float loadf(const void* p, long i, int f32) {
    return f32 ? ((const float*)p)[i] : bf2f(((const __hip_bfloat16*)p)[i]);
}
__device__ __forceinline__ unsigned short f2bf_bits(float f) {
    __hip_bfloat16 h = __float2bfloat16(f);
    return *(unsigned short*)&h;
}
__device__ __forceinline__ float bfu2f(unsigned short u) {
    return __uint_as_float((unsigned)u << 16);
}
__device__ __forceinline__ float lo16(unsigned v) { return __uint_as_float(v << 16); }
__device__ __forceinline__ float hi16(unsigned v) { return __uint_as_float(v & 0xffff0000u); }
__device__ __forceinline__ ushort4 pack4(f32x4 v) {
    ushort4 u;
    u.x = f2bf_bits(v[0]); u.y = f2bf_bits(v[1]);
    u.z = f2bf_bits(v[2]); u.w = f2bf_bits(v[3]);
    return u;
}
__device__ __forceinline__ ushort4 pack4s(f32x4 v, float s) {
    ushort4 u;
    u.x = f2bf_bits(s * v[0]); u.y = f2bf_bits(s * v[1]);
    u.z = f2bf_bits(s * v[2]); u.w = f2bf_bits(s * v[3]);
    return u;
}

// exclusive prefix over 256 threads; *total_sh gets block total (stable after call)
__device__ __forceinline__ int blk_excl_scan(int v, int t, int* wsum, int* total_sh) {
    __syncthreads();   // protect wsum/total reuse across consecutive calls
    int lane = t & 63, w = t >> 6;
    int x = v;
    #pragma unroll
    for (int s = 1; s < 64; s <<= 1) {
        int y = __shfl_up(x, s, 64);
        if (lane >= s) x += y;
    }
    if (lane == 63) wsum[w] = x;
    __syncthreads();
    if (t == 0) {
        int a = 0;
        #pragma unroll
        for (int k = 0; k < 4; ++k) { int tmp = wsum[k]; wsum[k] = a; a += tmp; }
        *total_sh = a;
    }
    __syncthreads();
    return x - v + wsum[w];
}

// flags[0]=edge_index int64, flags[1]=batch int64, flags[2]=floats are f32
__global__ void detect_kernel(const void* ei, const void* batch, const void* Wemb,
                              int* __restrict__ flags) {
    __shared__ int s_edge_nz, s_batch_nz, s_f32_cnt;
    int t = threadIdx.x;  // 64
    if (t == 0) { s_edge_nz = 0; s_batch_nz = 0; s_f32_cnt = 0; }
    __syncthreads();
    {   const int* w = (const int*)ei;
        long j = ((long)t * ((2L * EE) / 64)) | 1;
        if (w[j] != 0) atomicAdd(&s_edge_nz, 1);
    }
    {   const int* w = (const int*)batch;
        long j = ((long)(NN / 2) + (long)t * ((NN / 2) / 64)) | 1;
        if (j < NN && w[j] != 0) atomicAdd(&s_batch_nz, 1);
    }
    {   const unsigned short* w = (const unsigned short*)Wemb;
        unsigned short v = w[2 * t];
        int ex = (v >> 7) & 0xFF;
        if (v != 0 && ex >= 128) atomicAdd(&s_f32_cnt, 1);
    }
    __syncthreads();
    if (t == 0) {
        flags[0] = (s_edge_nz == 0) ? 1 : 0;
        flags[1] = (s_batch_nz == 0) ? 1 : 0;
        flags[2] = (s_f32_cnt >= 8) ? 1 : 0;
    }
}

struct Param { const void* src; float* dst; int src_n; int dst_n; };
struct Params12 { Param p[12]; };
struct WtDesc { const void* src; long src_off; unsigned short* dst; int K; int Kpad; };
struct WtDescs5 { WtDesc p[5]; };

// A: edge extract + bucket hist (LDS only) || conversions + zero-init
__global__ __launch_bounds__(256) void mega_conv_kernel(
    const void* __restrict__ x, const void* __restrict__ ei,
    const void* __restrict__ batch, const int* __restrict__ flags,
    unsigned short* __restrict__ xb, float* __restrict__ statmulti,
    float* __restrict__ hgsum, int* __restrict__ b32,
    unsigned* __restrict__ pk, unsigned char* __restrict__ bkt,
    int* __restrict__ bh, int* __restrict__ dcnt, Params12 P, WtDescs5 W)
{
    int b = blockIdx.x;
    int t = threadIdx.x;
    if (b < A_EDGE) {
        __shared__ int hist[NBKT];
        if (t < NBKT) hist[t] = 0;
        __syncthreads();
        int e0 = (b * 256 + t) * 4;
        if (e0 < EE) {
            const int* w = (const int*)ei;
            int4 sv, dv;
            if (flags[0]) {
                int4 u0 = *(const int4*)(w + 2L * e0);
                int4 u1 = *(const int4*)(w + 2L * e0 + 4);
                int4 v0 = *(const int4*)(w + 2L * (EE + e0));
                int4 v1 = *(const int4*)(w + 2L * (EE + e0) + 4);
                sv = make_int4(u0.x, u0.z, u1.x, u1.z);
                dv = make_int4(v0.x, v0.z, v1.x, v1.z);
            } else {
                sv = *(const int4*)(w + e0);
                dv = *(const int4*)(w + EE + e0);
            }
            int ss[4] = {sv.x, sv.y, sv.z, sv.w};
            int dd2[4] = {dv.x, dv.y, dv.z, dv.w};
            unsigned pk4[4], bk4[4];
            #pragma unroll
            for (int k = 0; k < 4; ++k) {
                unsigned s = min((unsigned)ss[k], (unsigned)(NN - 1));
                unsigned d = min((unsigned)dd2[k], (unsigned)(NN - 1));
                pk4[k] = (s << 8) | (d & 255u);
                bk4[k] = d >> 8;
                atomicAdd(&hist[bk4[k]], 1);
            }
            *(uint4*)(pk + e0) = make_uint4(pk4[0], pk4[1], pk4[2], pk4[3]);
            *(uchar4*)(bkt + e0) = make_uchar4((unsigned char)bk4[0], (unsigned char)bk4[1],
                                               (unsigned char)bk4[2], (unsigned char)bk4[3]);
        }
        __syncthreads();
        if (t < NBKT) bh[b * BHP + t] = hist[t];
    } else if (b < A_INIT) {
        int i = (b - A_EDGE) * 256 + t;
        if (i == 0) *dcnt = 0;
        if (i < LL * NCOPY * 256) statmulti[i] = 0.0f;
        if (i < GG * DD) hgsum[i] = 0.0f;
    } else if (b < A_REPACK) {
        // 8 cols per thread: float2/uint reads, one uint4 (16B) store
        int f32 = flags[2];
        long idx8 = (long)(b - A_INIT) * 256 + t;
        if (idx8 < (long)NN * 20) {
            int row = (int)(idx8 / 20);
            int c8 = (int)(idx8 - (long)row * 20) * 8;
            float v[8];
            if (c8 + 8 <= DIN) {
                if (f32) {
                    const float* xp = (const float*)x + (long)row * DIN + c8;
                    #pragma unroll
                    for (int k2 = 0; k2 < 4; ++k2) {
                        float2 f = *(const float2*)(xp + 2 * k2);  // 8B-aligned: 146*4%8==0
                        v[2 * k2] = f.x; v[2 * k2 + 1] = f.y;
                    }
                } else {
                    const unsigned* xp = (const unsigned*)((const unsigned short*)x +
                                                           (long)row * DIN + c8);
                    #pragma unroll
                    for (int k2 = 0; k2 < 4; ++k2) {
                        unsigned u = xp[k2];  // 4B-aligned: 146*2%4==0
                        v[2 * k2] = bfu2f((unsigned short)u);
                        v[2 * k2 + 1] = bfu2f((unsigned short)(u >> 16));
                    }
                }
            } else {
                #pragma unroll
                for (int k = 0; k < 8; ++k) {
                    int col = c8 + k;
                    v[k] = (col < DIN) ? loadf(x, (long)row * DIN + col, f32) : 0.0f;
                }
            }
            unsigned o[4];
            #pragma unroll
            for (int k2 = 0; k2 < 4; ++k2)
                o[k2] = (unsigned)f2bf_bits(v[2 * k2]) |
                        ((unsigned)f2bf_bits(v[2 * k2 + 1]) << 16);
            *(uint4*)(xb + (long)row * KP_EMB + c8) = make_uint4(o[0], o[1], o[2], o[3]);
        }
    } else if (b < A_BATCH) {
        int i = (b - A_REPACK) * 256 + t;
        if (i < NN) b32[i] = flags[1] ? ((const int*)batch)[2L * i] : ((const int*)batch)[i];
    } else if (b < A_PARAMS) {
        int f32 = flags[2];
        int bb = b - A_BATCH;
        const Param& e = P.p[bb >> 5];
        int idx = (bb & 31) * 256 + t;
        if (idx < e.dst_n)
            e.dst[idx] = (idx < e.src_n) ? loadf(e.src, idx, f32) : 0.0f;
    } else {
        int f32 = flags[2];
        int bb = b - A_PARAMS;
        int y = bb / 80;
        const WtDesc& e = W.p[y];
        int idx = (bb - y * 80) * 256 + t;
        if (idx < 128 * e.Kpad) {
            int n = idx / e.Kpad, k = idx - n * e.Kpad;
            float v = (k < e.K) ? loadf(e.src, e.src_off + (long)k * DD + n, f32) : 0.0f;
            e.dst[idx] = f2bf_bits(v);
        }
    }
}

// B: per bucket, exclusive-scan bh[0..NBE) column; write back in place; tot[b]=sum.
// Last-finishing block additionally scans tot -> base (replaces old bscan2 launch).
__global__ __launch_bounds__(256) void bscan_kernel(int* __restrict__ bh, int* __restrict__ tot,
                                                    int* __restrict__ base,
                                                    int* __restrict__ off_last,
                                                    int* __restrict__ dcnt) {
    __shared__ int wsum[4], total_sh;
    __shared__ int is_last;
    int b = blockIdx.x;
    int t = threadIdx.x;
    int carry = 0;
    #pragma unroll 1
    for (int c = 0; c < 4; ++c) {
        int i = c * 256 + t;
        int v = (i < NBE) ? bh[i * BHP + b] : 0;
        int excl = blk_excl_scan(v, t, wsum, &total_sh);
        if (i < NBE) bh[i * BHP + b] = excl + carry;
        carry += total_sh;
    }
    if (t == 0) {
        __hip_atomic_store(&tot[b], carry, __ATOMIC_RELEASE, __HIP_MEMORY_SCOPE_AGENT);
        int ticket = __hip_atomic_fetch_add(dcnt, 1, __ATOMIC_ACQ_REL, __HIP_MEMORY_SCOPE_AGENT);
        is_last = (ticket == NBKT - 1) ? 1 : 0;
    }
    __syncthreads();
    if (is_last) {
        int v = 0;
        if (t < NBKT)
            v = __hip_atomic_load(&tot[t], __ATOMIC_ACQUIRE, __HIP_MEMORY_SCOPE_AGENT);
        int excl = blk_excl_scan(v, t, wsum, &total_sh);
        if (t < NBKT) base[t] = excl;
        if (t == 0) { base[NBKT] = total_sh; *off_last = total_sh; }
    }
}

// ---- MFMA layouts (operand-SWAPPED form) ----
// mfma(b_frag, a_frag, acc): acc reg rg of slot t8 holds output col t8*16+quad*4+rg
// for node row rbase+rt*16+m  -> 4 consecutive cols per fragment = ushort4 store.

// C: emb MFMA gemm (blocks 0..390) || bucket scatter via LDS cursors (391..1172)
__global__ __launch_bounds__(256) void bucket_emb_kernel(
    const unsigned* __restrict__ pk, const unsigned char* __restrict__ bkt,
    const int* __restrict__ bh, const int* __restrict__ base,
    unsigned* __restrict__ bucketA,
    const unsigned short* __restrict__ Ab,   // xb [n][160] bf16
    const unsigned short* __restrict__ Wt,   // [128][160] bf16 transposed
    const float* __restrict__ bias,
    unsigned short* __restrict__ hb, int n)
{
    int t = threadIdx.x;
    if (blockIdx.x >= B_GEMM) {
        int bb = blockIdx.x - B_GEMM;
        __shared__ int cur[NBKT];
        if (t < NBKT) cur[t] = bh[bb * BHP + t] + base[t];
        __syncthreads();
        int e0 = (bb * 256 + t) * 4;
        if (e0 < EE) {
            uint4 p4 = *(const uint4*)(pk + e0);
            uchar4 b4 = *(const uchar4*)(bkt + e0);
            unsigned pks[4] = {p4.x, p4.y, p4.z, p4.w};
            unsigned bks[4] = {b4.x, b4.y, b4.z, b4.w};
            #pragma unroll
            for (int k = 0; k < 4; ++k) {
                int slot = atomicAdd(&cur[bks[k]], 1);
                bucketA[slot] = pks[k];
            }
        }
        return;
    }
    int r0 = blockIdx.x * 128;
    int lane = t & 63, w = t >> 6;
    int m = lane & 15, quad = lane >> 4;
    int rbase = r0 + w * 32;
    bf16x8 a[2][5];
    #pragma unroll
    for (int rt = 0; rt < 2; ++rt)
        #pragma unroll
        for (int c = 0; c < 5; ++c) {
            int rr = rbase + rt * 16 + m; if (rr > n - 1) rr = n - 1;
            a[rt][c] = *(const bf16x8*)(Ab + (long)rr * KP_EMB + c * 32 + quad * 8);
        }
    f32x4 acc[2][8];
    #pragma unroll
    for (int t8 = 0; t8 < 8; ++t8) {
        float4 bv = *(const float4*)&bias[t8 * 16 + quad * 4];
        f32x4 ai = {bv.x, bv.y, bv.z, bv.w};
        acc[0][t8] = ai; acc[1][t8] = ai;
    }
    #pragma unroll
    for (int t8 = 0; t8 < 8; ++t8) {
        #pragma unroll
        for (int c = 0; c < 5; ++c) {
            bf16x8 b = *(const bf16x8*)(Wt + (long)(t8 * 16 + m) * KP_EMB + c * 32 + quad * 8);
            acc[0][t8] = __builtin_amdgcn_mfma_f32_16x16x32_bf16(b, a[0][c], acc[0][t8], 0, 0, 0);
            acc[1][t8] = __builtin_amdgcn_mfma_f32_16x16x32_bf16(b, a[1][c], acc[1][t8], 0, 0, 0);
        }
    }
    #pragma unroll
    for (int rt = 0; rt < 2; ++rt) {
        int row = rbase + rt * 16 + m;
        if (row < n) {
            #pragma unroll
            for (int t8 = 0; t8 < 8; ++t8)
                *(ushort4*)(hb + (long)row * DD + t8 * 16 + quad * 4) = pack4(acc[rt][t8]);
        }
    }
}

// D: per-bucket CSR: LDS degree hist -> off/dinv; LDS cursors -> src_s
__global__ __launch_bounds__(256) void csr_kernel(
    const unsigned* __restrict__ bucketA, const int* __restrict__ base,
    int* __restrict__ off, float* __restrict__ dinv, int* __restrict__ src_s)
{
    __shared__ int dg[256], cur[256], wsum[4], total_sh;
    int b = blockIdx.x, t = threadIdx.x;
    int eb0 = base[b], eb1 = base[b + 1];
    dg[t] = 0;
    __syncthreads();
    for (int e = eb0 + t; e < eb1; e += 256)
        atomicAdd(&dg[bucketA[e] & 255u], 1);
    __syncthreads();
    int v = dg[t];
    int excl = blk_excl_scan(v, t, wsum, &total_sh);
    int node = b * 256 + t;
    if (node < NN) {
        off[node] = eb0 + excl;
        dinv[node] = rsqrtf((float)(v + 1));  // +1 self-loop
    }
    cur[t] = excl;
    __syncthreads();
    for (int e = eb0 + t; e < eb1; e += 256) {
        unsigned pv = bucketA[e];
        int r = atomicAdd(&cur[pv & 255u], 1);
        src_s[eb0 + r] = (int)(pv >> 8);
    }
}

// E: layer-0 gemm (mb = dinv * hb . W0)
__global__ __launch_bounds__(256) void gemm_plain_kernel(
    const unsigned short* __restrict__ Ab,   // hb
    const unsigned short* __restrict__ Wt,   // wt_gcn layer 0
    const float* __restrict__ dinv,
    unsigned short* __restrict__ Mb, int n)
{
    int t = threadIdx.x;
    int r0 = blockIdx.x * 128;
    int lane = t & 63, w = t >> 6;
    int m = lane & 15, quad = lane >> 4;
    int rbase = r0 + w * 32;
    bf16x8 a[2][4];
    #pragma unroll
    for (int rt = 0; rt < 2; ++rt)
        #pragma unroll
        for (int c = 0; c < 4; ++c) {
            int rr = rbase + rt * 16 + m; if (rr > n - 1) rr = n - 1;
            a[rt][c] = *(const bf16x8*)(Ab + (long)rr * DD + c * 32 + quad * 8);
        }
    float dvt[2];
    int rowt[2];
    #pragma unroll
    for (int rt = 0; rt < 2; ++rt) {
        int rr = rbase + rt * 16 + m;
        rowt[rt] = rr;
        if (rr > n - 1) rr = n - 1;
        dvt[rt] = dinv[rr];
    }
    f32x4 acc[2][8];
    #pragma unroll
    for (int t8 = 0; t8 < 8; ++t8) {
        f32x4 z = {0.f, 0.f, 0.f, 0.f};
        acc[0][t8] = z; acc[1][t8] = z;
    }
    #pragma unroll
    for (int t8 = 0; t8 < 8; ++t8) {
        #pragma unroll
        for (int c = 0; c < 4; ++c) {
            bf16x8 b = *(const bf16x8*)(Wt + (long)(t8 * 16 + m) * DD + c * 32 + quad * 8);
            acc[0][t8] = __builtin_amdgcn_mfma_f32_16x16x32_bf16(b, a[0][c], acc[0][t8], 0, 0, 0);
            acc[1][t8] = __builtin_amdgcn_mfma_f32_16x16x32_bf16(b, a[1][c], acc[1][t8], 0, 0, 0);
        }
    }
    #pragma unroll
    for (int rt = 0; rt < 2; ++rt) {
        if (rowt[rt] < n) {
            #pragma unroll
            for (int t8 = 0; t8 < 8; ++t8)
                *(ushort4*)(Mb + (long)rowt[rt] * DD + t8 * 16 + quad * 4) = pack4s(acc[rt][t8], dvt[rt]);
        }
    }
}

// fused: inline stats-finalize + hb += relu(bn(aggb)) (bf16 in-place) + MFMA
__global__ __launch_bounds__(256) void gemm_fused_kernel(
    const unsigned short* __restrict__ aggb, unsigned short* __restrict__ hb,
    const float* __restrict__ statmulti, const float* __restrict__ gamma,
    const float* __restrict__ beta, const float* __restrict__ dinv,
    const unsigned short* __restrict__ Wt, unsigned short* __restrict__ Mb, int n)
{
    __shared__ unsigned short As[128 * AST_L];
    __shared__ float bnsh[256];
    int t = threadIdx.x;
    int r0 = blockIdx.x * 128;
    {
        float s = 0.0f;
        #pragma unroll 8
        for (int k = 0; k < NCOPY; ++k) s += statmulti[k * 256 + t];
        bnsh[t] = s;
    }
    __syncthreads();
    {
        int c4 = (t & 31) * 4, rsub = t >> 5;  // 8 row substreams
        float inv_n = 1.0f / (float)n;
        float4 sm = *(const float4*)&bnsh[c4];
        float4 sq = *(const float4*)&bnsh[128 + c4];
        float4 ga = *(const float4*)&gamma[c4];
        float4 be = *(const float4*)&beta[c4];
        float4 mu, rs;
        mu.x = sm.x * inv_n; mu.y = sm.y * inv_n; mu.z = sm.z * inv_n; mu.w = sm.w * inv_n;
        rs.x = rsqrtf(sq.x * inv_n - mu.x * mu.x + BN_EPS) * ga.x;
        rs.y = rsqrtf(sq.y * inv_n - mu.y * mu.y + BN_EPS) * ga.y;
        rs.z = rsqrtf(sq.z * inv_n - mu.z * mu.z + BN_EPS) * ga.z;
        rs.w = rsqrtf(sq.w * inv_n - mu.w * mu.w + BN_EPS) * ga.w;
        #pragma unroll 4
        for (int i = 0; i < 16; ++i) {
            int row = i * 8 + rsub;
            int r = r0 + row;
            unsigned short o0 = 0, o1 = 0, o2 = 0, o3 = 0;
            if (r < n) {
                long g = (long)r * DD + c4;
                ushort4 au = *(const ushort4*)&aggb[g];
                ushort4 hu = *(const ushort4*)&hb[g];
                float h0 = bfu2f(hu.x) + fmaxf((bfu2f(au.x) - mu.x) * rs.x + be.x, 0.0f);
                float h1 = bfu2f(hu.y) + fmaxf((bfu2f(au.y) - mu.y) * rs.y + be.y, 0.0f);
                float h2 = bfu2f(hu.z) + fmaxf((bfu2f(au.z) - mu.z) * rs.z + be.z, 0.0f);
                float h3 = bfu2f(hu.w) + fmaxf((bfu2f(au.w) - mu.w) * rs.w + be.w, 0.0f);
                o0 = f2bf_bits(h0); o1 = f2bf_bits(h1);
                o2 = f2bf_bits(h2); o3 = f2bf_bits(h3);
                ushort4 ho; ho.x = o0; ho.y = o1; ho.z = o2; ho.w = o3;
                *(ushort4*)&hb[g] = ho;
            }
            unsigned short* dst = &As[row * AST_L + c4];
            dst[0] = o0; dst[1] = o1; dst[2] = o2; dst[3] = o3;
        }
    }
    __syncthreads();
    int lane = t & 63, w = t >> 6;
    int m = lane & 15, quad = lane >> 4;
    int rl = w * 32;
    int rbase = r0 + rl;
    bf16x8 a[2][4];
    #pragma unroll
    for (int rt = 0; rt < 2; ++rt)
        #pragma unroll
        for (int c = 0; c < 4; ++c)
            a[rt][c] = *(const bf16x8*)(As + (rl + rt * 16 + m) * AST_L + c * 32 + quad * 8);
    float dvt[2];
    int rowt[2];
    #pragma unroll
    for (int rt = 0; rt < 2; ++rt) {
        int rr = rbase + rt * 16 + m;
        rowt[rt] = rr;
        if (rr > n - 1) rr = n - 1;
        dvt[rt] = dinv[rr];
    }
    f32x4 acc[2][8];
    #pragma unroll
    for (int t8 = 0; t8 < 8; ++t8) {
        f32x4 z = {0.f, 0.f, 0.f, 0.f};
        acc[0][t8] = z; acc[1][t8] = z;
    }
    #pragma unroll
    for (int t8 = 0; t8 < 8; ++t8) {
        #pragma unroll
        for (int c = 0; c < 4; ++c) {
            bf16x8 b = *(const bf16x8*)(Wt + (long)(t8 * 16 + m) * DD + c * 32 + quad * 8);
            acc[0][t8] = __builtin_amdgcn_mfma_f32_16x16x32_bf16(b, a[0][c], acc[0][t8], 0, 0, 0);
            acc[1][t8] = __builtin_amdgcn_mfma_f32_16x16x32_bf16(b, a[1][c], acc[1][t8], 0, 0, 0);
        }
    }
    #pragma unroll
    for (int rt = 0; rt < 2; ++rt) {
        if (rowt[rt] < n) {
            #pragma unroll
            for (int t8 = 0; t8 < 8; ++t8)
                *(ushort4*)(Mb + (long)rowt[rt] * DD + t8 * 16 + quad * 4) = pack4s(acc[rt][t8], dvt[rt]);
        }
    }
}

// agg: wave-per-node, lane owns cols (2l,2l+1). SCALARIZED addressing: e/e1 and
// all gather indices forced to SGPR (readfirstlane) -> row loads are
// global_load_dword v, v_laneoff, s[rowbase] with zero per-lane address VALU.
__global__ __launch_bounds__(256) void agg_kernel(
    const unsigned* __restrict__ mb32, const int* __restrict__ off,
    const int* __restrict__ src_s,
    const float* __restrict__ dinv, const float* __restrict__ bias,
    unsigned* __restrict__ aggb32, float* __restrict__ statacc)
{
    __shared__ float2 ssum[4][64], ssq[4][64];
    int t = threadIdx.x;
    int wv = t >> 6, lane = t & 63;
    float2 bi = ((const float2*)bias)[lane];
    float2 sAcc = {0.0f, 0.0f}, qAcc = {0.0f, 0.0f};
    int i0 = (blockIdx.x * 4 + wv) * NPW;
    #pragma unroll 1
    for (int ni = 0; ni < NPW; ++ni) {
        int i = i0 + ni;
        if (i >= NN) break;
        int e  = __builtin_amdgcn_readfirstlane(off[i]);
        int e1 = __builtin_amdgcn_readfirstlane(off[i + 1]);
        unsigned vs = mb32[(long)i * 64 + lane];   // self-loop term (uniform base)
        float a0 = lo16(vs), a1 = hi16(vs);
        for (; e + 8 <= e1; e += 8) {
            int j0 = __builtin_amdgcn_readfirstlane(src_s[e + 0]);
            int j1 = __builtin_amdgcn_readfirstlane(src_s[e + 1]);
            int j2 = __builtin_amdgcn_readfirstlane(src_s[e + 2]);
            int j3 = __builtin_amdgcn_readfirstlane(src_s[e + 3]);
            int j4 = __builtin_amdgcn_readfirstlane(src_s[e + 4]);
            int j5 = __builtin_amdgcn_readfirstlane(src_s[e + 5]);
            int j6 = __builtin_amdgcn_readfirstlane(src_s[e + 6]);
            int j7 = __builtin_amdgcn_readfirstlane(src_s[e + 7]);
            unsigned v0 = mb32[(long)j0 * 64 + lane];
            unsigned v1 = mb32[(long)j1 * 64 + lane];
            unsigned v2 = mb32[(long)j2 * 64 + lane];
            unsigned v3 = mb32[(long)j3 * 64 + lane];
            unsigned v4 = mb32[(long)j4 * 64 + lane];
            unsigned v5 = mb32[(long)j5 * 64 + lane];
            unsigned v6 = mb32[(long)j6 * 64 + lane];
            unsigned v7 = mb32[(long)j7 * 64 + lane];
            a0 += lo16(v0); a1 += hi16(v0);
            a0 += lo16(v1); a1 += hi16(v1);
            a0 += lo16(v2); a1 += hi16(v2);
            a0 += lo16(v3); a1 += hi16(v3);
            a0 += lo16(v4); a1 += hi16(v4);
            a0 += lo16(v5); a1 += hi16(v5);
            a0 += lo16(v6); a1 += hi16(v6);
            a0 += lo16(v7); a1 += hi16(v7);
        }
        for (; e + 4 <= e1; e += 4) {
            int j0 = __builtin_amdgcn_readfirstlane(src_s[e + 0]);
            int j1 = __builtin_amdgcn_readfirstlane(src_s[e + 1]);
            int j2 = __builtin_amdgcn_readfirstlane(src_s[e + 2]);
            int j3 = __builtin_amdgcn_readfirstlane(src_s[e + 3]);
            unsigned v0 = mb32[(long)j0 * 64 + lane];
            unsigned v1 = mb32[(long)j1 * 64 + lane];
            unsigned v2 = mb32[(long)j2 * 64 + lane];
            unsigned v3 = mb32[(long)j3 * 64 + lane];
            a0 += lo16(v0); a1 += hi16(v0);
            a0 += lo16(v1); a1 += hi16(v1);
            a0 += lo16(v2); a1 += hi16(v2);
            a0 += lo16(v3); a1 += hi16(v3);
        }
        for (; e < e1; ++e) {
            int j = __builtin_amdgcn_readfirstlane(src_s[e]);
            unsigned v = mb32[(long)j * 64 + lane];
            a0 += lo16(v); a1 += hi16(v);
        }
        float di = dinv[i];
        float o0 = fmaf(di, a0, bi.x);
        float o1 = fmaf(di, a1, bi.y);
        aggb32[(long)i * 64 + lane] = ((unsigned)f2bf_bits(o1) << 16) | f2bf_bits(o0);
        sAcc.x += o0; sAcc.y += o1;
        qAcc.x += o0 * o0; qAcc.y += o1 * o1;
    }
    ssum[wv][lane] = sAcc; ssq[wv][lane] = qAcc;
    __syncthreads();
    if (wv == 0) {
        float2 s0 = ssum[0][lane], s1 = ssum[1][lane], s2 = ssum[2][lane], s3 = ssum[3][lane];
        float2 q0 = ssq[0][lane], q1 = ssq[1][lane], q2 = ssq[2][lane], q3 = ssq[3][lane];
        float sx = s0.x + s1.x + s2.x + s3.x;
        float sy = s0.y + s1.y + s2.y + s3.y;
        float qx = q0.x + q1.x + q2.x + q3.x;
        float qy = q0.y + q1.y + q2.y + q3.y;
        float* copy = statacc + (blockIdx.x & (NCOPY - 1)) * 256;
        atomicAdd(&copy[2 * lane], sx);
        atomicAdd(&copy[2 * lane + 1], sy);
        atomicAdd(&copy[128 + 2 * lane], qx);
        atomicAdd(&copy[128 + 2 * lane + 1], qy);
    }
}

// pooling with inline stats-finalize + fused final BN+relu+residual (bf16 inputs)
__global__ void pool1_kernel(const unsigned short* __restrict__ hb,
                             const unsigned short* __restrict__ aggb,
                             const float* __restrict__ statmulti,
                             const float* __restrict__ gamma, const float* __restrict__ beta,
                             const int* __restrict__ b32, float* __restrict__ hgsum, int n) {
    __shared__ float bnsh[256];
    int t = threadIdx.x;
    {
        float s = 0.0f;
        #pragma unroll 8
        for (int k = 0; k < NCOPY; ++k) s += statmulti[k * 256 + t];
        bnsh[t] = s;
    }
    __syncthreads();
    int c4 = (t & 31) * 4, rsub = t >> 5;
    float inv_n = 1.0f / (float)n;
    float4 sm = *(const float4*)&bnsh[c4];
    float4 sq = *(const float4*)&bnsh[128 + c4];
    float4 ga = *(const float4*)&gamma[c4];
    float4 be = *(const float4*)&beta[c4];
    float4 mu, rs;
    mu.x = sm.x * inv_n; mu.y = sm.y * inv_n; mu.z = sm.z * inv_n; mu.w = sm.w * inv_n;
    rs.x = rsqrtf(sq.x * inv_n - mu.x * mu.x + BN_EPS) * ga.x;
    rs.y = rsqrtf(sq.y * inv_n - mu.y * mu.y + BN_EPS) * ga.y;
    rs.z = rsqrtf(sq.z * inv_n - mu.z * mu.z + BN_EPS) * ga.z;
    rs.w = rsqrtf(sq.w * inv_n - mu.w * mu.w + BN_EPS) * ga.w;
    int rows_pb = (n + gridDim.x - 1) / gridDim.x;
    int r0 = blockIdx.x * rows_pb;
    int r1 = min(n, r0 + rows_pb);
    float4 acc = {0, 0, 0, 0};
    int gcur = -1;
    for (int r = r0 + rsub; r < r1; r += 8) {
        int g = b32[r];
        if (g != gcur) {
            if (gcur >= 0) {
                atomicAdd(&hgsum[gcur * DD + c4 + 0], acc.x);
                atomicAdd(&hgsum[gcur * DD + c4 + 1], acc.y);
                atomicAdd(&hgsum[gcur * DD + c4 + 2], acc.z);
                atomicAdd(&hgsum[gcur * DD + c4 + 3], acc.w);
            }
            acc.x = acc.y = acc.z = acc.w = 0.0f;
            gcur = ((unsigned)g < (unsigned)GG) ? g : -1;
        }
        if (gcur >= 0) {
            long ix = (long)r * DD + c4;
            ushort4 au = *(const ushort4*)&aggb[ix];
            ushort4 hu = *(const ushort4*)&hb[ix];
            acc.x += bfu2f(hu.x) + fmaxf((bfu2f(au.x) - mu.x) * rs.x + be.x, 0.0f);
            acc.y += bfu2f(hu.y) + fmaxf((bfu2f(au.y) - mu.y) * rs.y + be.y, 0.0f);
            acc.z += bfu2f(hu.z) + fmaxf((bfu2f(au.z) - mu.z) * rs.z + be.z, 0.0f);
            acc.w += bfu2f(hu.w) + fmaxf((bfu2f(au.w) - mu.w) * rs.w + be.w, 0.0f);
        }
    }
    if (gcur >= 0) {
        atomicAdd(&hgsum[gcur * DD + c4 + 0], acc.x);
        atomicAdd(&hgsum[gcur * DD + c4 + 1], acc.y);
        atomicAdd(&hgsum[gcur * DD + c4 + 2], acc.z);
        atomicAdd(&hgsum[gcur * DD + c4 + 3], acc.w);
    }
}

__device__ int lower_bound_i(const int* __restrict__ a, int n, int v) {
    int lo = 0, hi = n;
    while (lo < hi) {
        int mid = (lo + hi) >> 1;
        if (a[mid] < v) lo = mid + 1; else hi = mid;
    }
    return lo;
}

// readout with fused mean-pool finalize
__global__ void readout_kernel(const float* __restrict__ hgsum, const int* __restrict__ b32,
                               const float* __restrict__ W1, const float* __restrict__ b1,
                               const float* __restrict__ W2, const float* __restrict__ b2,
                               const float* __restrict__ W3, const float* __restrict__ b3,
                               const int* __restrict__ flags, void* __restrict__ out, int n) {
    int f32 = flags[2];
    int g = blockIdx.x;
    int t = threadIdx.x;
    __shared__ float hgs[DD];
    __shared__ float z1[DD / 2];
    __shared__ float z2[DD / 4];
    int lo = lower_bound_i(b32, n, g);
    int hi = lower_bound_i(b32, n, g + 1);
    float invc = 1.0f / fmaxf((float)(hi - lo), 1.0f);
    hgs[t] = hgsum[g * DD + t] * invc;
    __syncthreads();
    if (t < DD / 2) {
        float acc = b1[t];
        #pragma unroll 8
        for (int k = 0; k < DD; ++k) acc = fmaf(hgs[k], W1[k * (DD / 2) + t], acc);
        z1[t] = fmaxf(acc, 0.0f);
    }
    __syncthreads();
    if (t < DD / 4) {
        float acc = b2[t];
        #pragma unroll 8
        for (int k = 0; k < DD / 2; ++k) acc = fmaf(z1[k], W2[k * (DD / 4) + t], acc);
        z2[t] = fmaxf(acc, 0.0f);
    }
    __syncthreads();
    if (t < NC) {
        float acc = b3[t];
        #pragma unroll 8
        for (int k = 0; k < DD / 4; ++k) acc = fmaf(z2[k], W3[k * NC + t], acc);
        if (f32) ((float*)out)[g * NC + t] = acc;
        else     ((__hip_bfloat16*)out)[g * NC + t] = __float2bfloat16(acc);
    }
}

extern "C" void kernel_launch(void* const* d_in, const int* in_sizes, int n_in,
                              void* d_out, int out_size, void* d_ws, size_t ws_size,
                              hipStream_t stream) {
    const void* x      = d_in[0];
    const void* ei     = d_in[1];
    const void* batch  = d_in[2];
    const void* W_emb  = d_in[3];
    const void* b_emb  = d_in[4];
    const void* W_gcn  = d_in[5];
    const void* b_gcn  = d_in[6];
    const void* bn_g   = d_in[7];
    const void* bn_b   = d_in[8];
    const void* W_r1   = d_in[9];
    const void* b_r1   = d_in[10];
    const void* W_r2   = d_in[11];
    const void* b_r2   = d_in[12];
    const void* W_r3   = d_in[13];
    const void* b_r3   = d_in[14];

    char* p = (char*)d_ws;
    auto alloc = [&](size_t bytes) -> void* {
        void* r = (void*)p;
        p += (bytes + 255) & ~(size_t)255;
        return r;
    };
    int*   flags  = (int*)alloc(64 * 4);
    int*   dcnt   = (int*)alloc(64 * 4);
    float* statmulti = (float*)alloc((size_t)LL * NCOPY * 256 * 4);
    float* hgsum  = (float*)alloc((size_t)GG * DD * 4);
    int*   off    = (int*)alloc((size_t)(NN + 1) * 4);
    float* dinv   = (float*)alloc((size_t)NN * 4);
    int*   b32    = (int*)alloc((size_t)NN * 4);
    int*   src_s  = (int*)alloc((size_t)EE * 4);
    unsigned* pk  = (unsigned*)alloc((size_t)EE * 4);
    unsigned char* bkt = (unsigned char*)alloc((size_t)EE);
    int*   bh     = (int*)alloc((size_t)NBE * BHP * 4);
    int*   tot    = (int*)alloc(256 * 4);
    int*   base   = (int*)alloc(256 * 4);
    unsigned* bucketA = (unsigned*)alloc((size_t)EE * 4);
    unsigned short* hb = (unsigned short*)alloc((size_t)NN * DD * 2);
    unsigned short* mb = (unsigned short*)alloc((size_t)NN * DD * 2);
    unsigned short* aggb = (unsigned short*)alloc((size_t)NN * DD * 2);
    unsigned short* xb = (unsigned short*)alloc((size_t)NN * KP_EMB * 2);
    // canonical params
    unsigned short* wt_emb = (unsigned short*)alloc((size_t)DD * KP_EMB * 2);
    unsigned short* wt_gcn = (unsigned short*)alloc((size_t)LL * DD * DD * 2);
    float* b_emb32 = (float*)alloc(DD * 4);
    float* b_gcn32 = (float*)alloc((size_t)LL * DD * 4);
    float* bng32   = (float*)alloc((size_t)LL * DD * 4);
    float* bnb32   = (float*)alloc((size_t)LL * DD * 4);
    float* wr1     = (float*)alloc((size_t)DD * (DD / 2) * 4);
    float* br1     = (float*)alloc((DD / 2) * 4);
    float* wr2     = (float*)alloc((size_t)(DD / 2) * (DD / 4) * 4);
    float* br2     = (float*)alloc((DD / 4) * 4);
    float* wr3     = (float*)alloc((size_t)(DD / 4) * NC * 4);
    float* br3     = (float*)alloc(NC * 4);

    detect_kernel<<<1, 64, 0, stream>>>(ei, batch, W_emb, flags);

    Params12 P;
    P.p[0]  = { b_emb, b_emb32, DD, DD };
    P.p[1]  = { b_gcn, b_gcn32, LL * DD, LL * DD };
    P.p[2]  = { bn_g,  bng32,   LL * DD, LL * DD };
    P.p[3]  = { bn_b,  bnb32,   LL * DD, LL * DD };
    P.p[4]  = { W_r1,  wr1,     DD * (DD / 2), DD * (DD / 2) };
    P.p[5]  = { b_r1,  br1,     DD / 2, DD / 2 };
    P.p[6]  = { W_r2,  wr2,     (DD / 2) * (DD / 4), (DD / 2) * (DD / 4) };
    P.p[7]  = { b_r2,  br2,     DD / 4, DD / 4 };
    P.p[8]  = { W_r3,  wr3,     (DD / 4) * NC, (DD / 4) * NC };
    P.p[9]  = { b_r3,  br3,     NC, NC };
    P.p[10] = { b_r3,  br3,     0, 0 };
    P.p[11] = { b_r3,  br3,     0, 0 };

    WtDescs5 W;
    W.p[0] = { W_emb, 0,            wt_emb,                DIN, KP_EMB };
    W.p[1] = { W_gcn, 0L * DD * DD, wt_gcn + 0L * DD * DD, DD,  DD };
    W.p[2] = { W_gcn, 1L * DD * DD, wt_gcn + 1L * DD * DD, DD,  DD };
    W.p[3] = { W_gcn, 2L * DD * DD, wt_gcn + 2L * DD * DD, DD,  DD };
    W.p[4] = { W_gcn, 3L * DD * DD, wt_gcn + 3L * DD * DD, DD,  DD };

    mega_conv_kernel<<<A_WT, 256, 0, stream>>>(x, ei, batch, flags, xb, statmulti,
                                               hgsum, b32, pk, bkt, bh, dcnt, P, W);

    bscan_kernel<<<NBKT, 256, 0, stream>>>(bh, tot, base, off + NN, dcnt);

    bucket_emb_kernel<<<C_TOT, 256, 0, stream>>>(pk, bkt, bh, base, bucketA,
                                                 xb, wt_emb, b_emb32, hb, NN);

    csr_kernel<<<NBKT, 256, 0, stream>>>(bucketA, base, off, dinv, src_s);

    gemm_plain_kernel<<<(NN + 127) / 128, 256, 0, stream>>>(hb, wt_gcn, dinv, mb, NN);

    int ngemm = (NN + 127) / 128;  // 391
    int nagg = (NN + 4 * NPW - 1) / (4 * NPW);  // 3125 blocks (16 nodes/block)
    for (int l = 0; l < LL; ++l) {
        if (l > 0) {
            gemm_fused_kernel<<<ngemm, 256, 0, stream>>>(
                aggb, hb, statmulti + (size_t)(l - 1) * NCOPY * 256,
                bng32 + (l - 1) * DD, bnb32 + (l - 1) * DD,
                dinv, wt_gcn + (size_t)l * DD * DD, mb, NN);
        }
        agg_kernel<<<nagg, 256, 0, stream>>>((const unsigned*)mb, off, src_s, dinv,
                                             b_gcn32 + l * DD, (unsigned*)aggb,
                                             statmulti + (size_t)l * NCOPY * 256);
    }

    pool1_kernel<<<512, 256, 0, stream>>>(hb, aggb, statmulti + (size_t)(LL - 1) * NCOPY * 256,
                                          bng32 + (LL - 1) * DD, bnb32 + (LL - 1) * DD,
                                          b32, hgsum, NN);
    readout_kernel<<<GG, DD, 0, stream>>>(hgsum, b32, wr1, br1, wr2, br2, wr3, br3,
                                          flags, d_out, NN);
}